// Round 4
// baseline (846.098 us; speedup 1.0000x reference)
//
#include <hip/hip_runtime.h>

#define NB 4
#define NH 16
#define NS 2048
#define ND 64
#define PST 2052  // P leading-dim pad (bf16 elems); row stride 4104 B

typedef __attribute__((ext_vector_type(8))) short short8;
typedef __attribute__((ext_vector_type(4))) short short4v;
typedef __attribute__((ext_vector_type(4))) float floatx4;
typedef __attribute__((ext_vector_type(2))) float floatx2;
typedef __attribute__((ext_vector_type(4))) int intx4;
typedef __attribute__((ext_vector_type(2))) unsigned uintx2;

__device__ __forceinline__ unsigned short f2bf(float f) {
  unsigned u = __builtin_bit_cast(unsigned, f);
  u = (u + 0x7FFFu + ((u >> 16) & 1u)) >> 16;  // RNE
  return (unsigned short)u;
}
__device__ __forceinline__ float bf2f(unsigned short s) {
  unsigned u = ((unsigned)s) << 16;
  return __builtin_bit_cast(float, u);
}

// ---- prep: K fp32 -> bf16, same [b,h,k,d] layout ----
__global__ __launch_bounds__(256) void prep_k_kernel(const float* __restrict__ K,
                                                     unsigned short* __restrict__ kb) {
  size_t i = ((size_t)blockIdx.x * 256 + threadIdx.x) * 4;
  floatx4 v = *(const floatx4*)(K + i);
  unsigned long long o = 0;
  o |= (unsigned long long)f2bf(v[0]);
  o |= (unsigned long long)f2bf(v[1]) << 16;
  o |= (unsigned long long)f2bf(v[2]) << 32;
  o |= (unsigned long long)f2bf(v[3]) << 48;
  *(unsigned long long*)(kb + i) = o;
}

// ---- prep: V [bh][k][d] fp32 -> VT [bh][d][k] bf16 ----
__global__ __launch_bounds__(256) void prep_vt_kernel(const float* __restrict__ V,
                                                      unsigned short* __restrict__ vt) {
  __shared__ float tile[64][65];
  int kc = blockIdx.x & 31;
  int bh = blockIdx.x >> 5;
  int k0 = kc * 64;
  const float* src = V + ((size_t)bh * NS + k0) * ND;
  int t = threadIdx.x;
  int r0 = t >> 4;
  int c = (t & 15) * 4;
  for (int rr = 0; rr < 4; ++rr) {
    int r = rr * 16 + r0;
    floatx4 v = *(const floatx4*)(src + (size_t)r * ND + c);
    tile[r][c + 0] = v[0]; tile[r][c + 1] = v[1];
    tile[r][c + 2] = v[2]; tile[r][c + 3] = v[3];
  }
  __syncthreads();
  unsigned short* dst = vt + (size_t)bh * ND * NS + k0;
  for (int i = 0; i < 16; ++i) {
    int lin = i * 256 + t;
    int d = lin >> 6, k = lin & 63;
    dst[(size_t)d * NS + k] = f2bf(tile[k][d]);
  }
}

// ---- fused attention ----
// 16-row q-tile, 512 threads = 8 waves; wave w owns k-strip [256w, 256w+256).
// Swapped QK (mfma(K,Q)) -> C[k][q]: lane = q-col, regs = 4 consecutive k.
__global__ __launch_bounds__(512, 4) void attn_kernel(
    const float* __restrict__ Q,
    const unsigned short* __restrict__ Kb,
    const unsigned short* __restrict__ VT,
    const int* __restrict__ mask,
    const float* __restrict__ bias,
    float* __restrict__ out,
    float* __restrict__ attn) {
  extern __shared__ char smem[];
  unsigned short* P = (unsigned short*)smem;      // [16][PST] bf16 (unnormalized exp)
  float* sums = (float*)(smem + 16 * PST * 2);    // [8 waves][16 rows]

  const int bid = blockIdx.x;
  const int b = bid & 3;                // batch fastest -> bias tile shared via L2/L3
  const int qt = (bid >> 2) & 127;
  const int h = bid >> 9;
  const int q0 = qt * 16;

  const int tid = threadIdx.x;
  const int wave = tid >> 6;  // 0..7
  const int lane = tid & 63;
  const int lg = lane >> 4;   // 0..3
  const int lc = lane & 15;   // 0..15
  const int lg4 = lg * 4;
  const int lg8 = lg * 8;

  const size_t bh = (size_t)(b * NH + h);

  // Q B-frags (n = q = lc), 1/8 scale folded into the bf16 convert (2^-3: exact)
  short8 aq0, aq1;
  {
    const float* qrow = Q + (bh * NS + (size_t)(q0 + lc)) * ND + lg8;
    floatx4 f0 = *(const floatx4*)(qrow);
    floatx4 f1 = *(const floatx4*)(qrow + 4);
    floatx4 f2 = *(const floatx4*)(qrow + 32);
    floatx4 f3 = *(const floatx4*)(qrow + 36);
#pragma unroll
    for (int j = 0; j < 4; ++j) {
      aq0[j] = (short)f2bf(f0[j] * 0.125f);
      aq0[4 + j] = (short)f2bf(f1[j] * 0.125f);
      aq1[j] = (short)f2bf(f2[j] * 0.125f);
      aq1[4 + j] = (short)f2bf(f3[j] * 0.125f);
    }
  }

  const unsigned short* kp = Kb + bh * NS * ND + (size_t)lc * ND + lg8;
  const float* bp = bias + ((size_t)h * NS + (size_t)(q0 + lc)) * NS + lg4;
  const int* mp = mask + b * NS + lg4;
  const int ksb = wave * 256;
  float psum = 0.f;

  // ---- QK^T + bias + mask + exp -> P; named 4-stage ring, fenced ----
  short8 kA0, kA1, kA2, kA3, kB0, kB1, kB2, kB3;
  floatx4 bV0, bV1, bV2, bV3;
  intx4 mV0, mV1, mV2, mV3;

#define FENCE asm volatile("" ::: "memory")

#define QK_LOAD(S, IT) {                                              \
    const int k0_ = ksb + (IT) * 16;                                  \
    kA##S = *(const short8*)(kp + (size_t)k0_ * ND);                  \
    kB##S = *(const short8*)(kp + (size_t)k0_ * ND + 32);             \
    bV##S = *(const floatx4*)(bp + k0_);                              \
    mV##S = *(const intx4*)(mp + k0_);                                \
  }

#define QK_COMP(S, IT) {                                              \
    const int k0_ = ksb + (IT) * 16;                                  \
    floatx4 c;                                                        \
    c[0] = bV##S[0]; c[1] = bV##S[1];                                 \
    c[2] = bV##S[2]; c[3] = bV##S[3];                                 \
    c = __builtin_amdgcn_mfma_f32_16x16x32_bf16(kA##S, aq0, c, 0, 0, 0); \
    c = __builtin_amdgcn_mfma_f32_16x16x32_bf16(kB##S, aq1, c, 0, 0, 0); \
    float p0 = mV##S[0] ? __expf(c[0]) : 0.f;                         \
    float p1 = mV##S[1] ? __expf(c[1]) : 0.f;                         \
    float p2 = mV##S[2] ? __expf(c[2]) : 0.f;                         \
    float p3 = mV##S[3] ? __expf(c[3]) : 0.f;                         \
    psum += (p0 + p1) + (p2 + p3);                                    \
    uintx2 w_;                                                        \
    w_[0] = (unsigned)f2bf(p0) | ((unsigned)f2bf(p1) << 16);          \
    w_[1] = (unsigned)f2bf(p2) | ((unsigned)f2bf(p3) << 16);          \
    *(uintx2*)((char*)P + (size_t)lc * (PST * 2) + (size_t)(k0_ + lg4) * 2) = w_; \
  }

  QK_LOAD(0, 0) QK_LOAD(1, 1) QK_LOAD(2, 2) FENCE;
  QK_LOAD(3, 3)  FENCE; QK_COMP(0, 0)
  QK_LOAD(0, 4)  FENCE; QK_COMP(1, 1)
  QK_LOAD(1, 5)  FENCE; QK_COMP(2, 2)
  QK_LOAD(2, 6)  FENCE; QK_COMP(3, 3)
  QK_LOAD(3, 7)  FENCE; QK_COMP(0, 4)
  QK_LOAD(0, 8)  FENCE; QK_COMP(1, 5)
  QK_LOAD(1, 9)  FENCE; QK_COMP(2, 6)
  QK_LOAD(2, 10) FENCE; QK_COMP(3, 7)
  QK_LOAD(3, 11) FENCE; QK_COMP(0, 8)
  QK_LOAD(0, 12) FENCE; QK_COMP(1, 9)
  QK_LOAD(1, 13) FENCE; QK_COMP(2, 10)
  QK_LOAD(2, 14) FENCE; QK_COMP(3, 11)
  QK_LOAD(3, 15) FENCE; QK_COMP(0, 12)
  QK_COMP(1, 13) QK_COMP(2, 14) QK_COMP(3, 15)
#undef QK_LOAD
#undef QK_COMP

  // row-sum: lanes {l, l^16, l^32, l^48} share q=lc
  psum += __shfl_xor(psum, 16);
  psum += __shfl_xor(psum, 32);
  if (lane < 16) sums[wave * 16 + lane] = psum;
  __syncthreads();

  // row scales for this wave's 2 attn-output rows
  const int wrow0 = wave * 2;
  float inv0, inv1;
  {
    float t0 = 0.f, t1 = 0.f;
#pragma unroll
    for (int w = 0; w < 8; ++w) {
      t0 += sums[w * 16 + wrow0];
      t1 += sums[w * 16 + wrow0 + 1];
    }
    inv0 = 1.f / t0;
    inv1 = 1.f / t1;
  }

  // ---- PV (own-strip) interleaved with attn-write stream ----
  const size_t abase = (bh * NS + (size_t)q0) * NS;

#define WRITECHUNK(CI) {                                                     \
    const int row_ = wrow0 + ((CI) >> 3);                                    \
    const float inv_ = (((CI) >> 3) == 0) ? inv0 : inv1;                     \
    const int col_ = ((CI) & 7) * 256 + lane * 4;                            \
    short4v pv_ = *(const short4v*)(P + row_ * PST + col_);                  \
    floatx4 f_;                                                              \
    f_[0] = bf2f((unsigned short)pv_[0]) * inv_;                             \
    f_[1] = bf2f((unsigned short)pv_[1]) * inv_;                             \
    f_[2] = bf2f((unsigned short)pv_[2]) * inv_;                             \
    f_[3] = bf2f((unsigned short)pv_[3]) * inv_;                             \
    __builtin_nontemporal_store(f_, (floatx4*)(attn + abase +                \
                                               (size_t)row_ * NS + col_));   \
  }

  floatx4 o0 = {0.f, 0.f, 0.f, 0.f}, o1 = {0.f, 0.f, 0.f, 0.f};
  floatx4 o2 = {0.f, 0.f, 0.f, 0.f}, o3 = {0.f, 0.f, 0.f, 0.f};
  const unsigned short* vp = VT + bh * (size_t)ND * NS + (size_t)lc * NS + lg8;

  short8 va0, va1, va2, va3, vb0, vb1, vb2, vb3;

#define PV_LOAD(BUF, IT) {                                      \
    const int k0_ = ksb + (IT) * 32;                            \
    BUF##0 = *(const short8*)(vp + (size_t)(0 * 16) * NS + k0_); \
    BUF##1 = *(const short8*)(vp + (size_t)(1 * 16) * NS + k0_); \
    BUF##2 = *(const short8*)(vp + (size_t)(2 * 16) * NS + k0_); \
    BUF##3 = *(const short8*)(vp + (size_t)(3 * 16) * NS + k0_); \
  }

#define PV_COMP(BUF, IT) {                                              \
    const int k0_ = ksb + (IT) * 32;                                    \
    const unsigned short* pr = P + (size_t)lc * PST + k0_ + lg8;        \
    short4v lo = *(const short4v*)pr;                                   \
    short4v hi = *(const short4v*)(pr + 4);                             \
    short8 pa = __builtin_shufflevector(lo, hi, 0, 1, 2, 3, 4, 5, 6, 7); \
    o0 = __builtin_amdgcn_mfma_f32_16x16x32_bf16(pa, BUF##0, o0, 0, 0, 0); \
    o1 = __builtin_amdgcn_mfma_f32_16x16x32_bf16(pa, BUF##1, o1, 0, 0, 0); \
    o2 = __builtin_amdgcn_mfma_f32_16x16x32_bf16(pa, BUF##2, o2, 0, 0, 0); \
    o3 = __builtin_amdgcn_mfma_f32_16x16x32_bf16(pa, BUF##3, o3, 0, 0, 0); \
  }

  PV_LOAD(va, 0)
  PV_LOAD(vb, 1) WRITECHUNK(0)  WRITECHUNK(1)  FENCE; PV_COMP(va, 0)
  PV_LOAD(va, 2) WRITECHUNK(2)  WRITECHUNK(3)  FENCE; PV_COMP(vb, 1)
  PV_LOAD(vb, 3) WRITECHUNK(4)  WRITECHUNK(5)  FENCE; PV_COMP(va, 2)
  PV_LOAD(va, 4) WRITECHUNK(6)  WRITECHUNK(7)  FENCE; PV_COMP(vb, 3)
  PV_LOAD(vb, 5) WRITECHUNK(8)  WRITECHUNK(9)  FENCE; PV_COMP(va, 4)
  PV_LOAD(va, 6) WRITECHUNK(10) WRITECHUNK(11) FENCE; PV_COMP(vb, 5)
  PV_LOAD(vb, 7) WRITECHUNK(12) WRITECHUNK(13) FENCE; PV_COMP(va, 6)
  WRITECHUNK(14) WRITECHUNK(15) FENCE; PV_COMP(vb, 7)
#undef PV_LOAD
#undef PV_COMP
#undef WRITECHUNK

  __syncthreads();  // all P reads done; reuse P area for O reduction

  float* Ored = (float*)smem;  // [8 waves][16 rows][64 cols] = 32 KB
#define OWRITE(OV, DT) {                                                   \
    _Pragma("unroll") for (int r = 0; r < 4; ++r)                          \
      Ored[((size_t)wave * 16 + lg4 + r) * 64 + (DT) * 16 + lc] = OV[r];   \
  }
  OWRITE(o0, 0) OWRITE(o1, 1) OWRITE(o2, 2) OWRITE(o3, 3)
#undef OWRITE
  __syncthreads();

  {
    const int q = tid >> 5;          // 0..15
    const int c2 = (tid & 31) * 2;   // 0..62
    floatx2 acc = {0.f, 0.f};
#pragma unroll
    for (int w = 0; w < 8; ++w) {
      const float* p = Ored + ((size_t)w * 16 + q) * 64 + c2;
      acc[0] += p[0];
      acc[1] += p[1];
    }
    float tot = 0.f;
#pragma unroll
    for (int w = 0; w < 8; ++w) tot += sums[w * 16 + q];
    const float inv = 1.f / tot;
    floatx2 res;
    res[0] = acc[0] * inv;
    res[1] = acc[1] * inv;
    __builtin_nontemporal_store(res, (floatx2*)(out + (bh * NS + (size_t)(q0 + q)) * ND + c2));
  }
}

extern "C" void kernel_launch(void* const* d_in, const int* in_sizes, int n_in,
                              void* d_out, int out_size, void* d_ws, size_t ws_size,
                              hipStream_t stream) {
  const float* Q = (const float*)d_in[0];
  const float* K = (const float*)d_in[1];
  const float* V = (const float*)d_in[2];
  const int* mask = (const int*)d_in[3];
  const float* bias = (const float*)d_in[4];

  float* out = (float*)d_out;
  float* attn = out + (size_t)NB * NH * NS * ND;  // outputs concatenated: (output, attn)

  unsigned short* kb = (unsigned short*)d_ws;
  unsigned short* vt = kb + (size_t)NB * NH * NS * ND;

  const int lds_bytes = 16 * PST * 2 + 8 * 16 * 4;  // 66176
  (void)hipFuncSetAttribute((const void*)attn_kernel,
                            hipFuncAttributeMaxDynamicSharedMemorySize, lds_bytes);

  prep_k_kernel<<<(NB * NH * NS * ND) / (256 * 4), 256, 0, stream>>>(K, kb);
  prep_vt_kernel<<<NB * NH * (NS / 64), 256, 0, stream>>>(V, vt);
  attn_kernel<<<NB * NH * (NS / 16), 512, lds_bytes, stream>>>(Q, kb, vt, mask, bias, out, attn);
}